// Round 1
// baseline (94.403 us; speedup 1.0000x reference)
//
#include <hip/hip_runtime.h>

// Rowwise cosine similarity * scale:
//   out[i] = scale * dot(x[i], p[i]) / (max(||x[i]||,eps) * max(||p[i]||,eps))
// n = 131072 rows, d = 512 f32. Memory-bound: ~537 MB read per call.
//
// One 64-lane wave per row; each lane loads 2 float4 from each of x,p
// (64 * 8 = 512 elements), accumulates xx/pp/xp partials, butterfly-reduces
// across the wave, lane 0 writes the result.

#define EPSF 1e-12f

__global__ __launch_bounds__(256) void cossim_rows_kernel(
    const float* __restrict__ x,
    const float* __restrict__ p,
    const float* __restrict__ scale,
    float* __restrict__ out,
    int n)
{
    const int gwave = (int)((blockIdx.x * (unsigned)blockDim.x + threadIdx.x) >> 6);
    const int lane  = threadIdx.x & 63;
    if (gwave >= n) return;

    const float4* __restrict__ xr =
        reinterpret_cast<const float4*>(x + (size_t)gwave * 512);
    const float4* __restrict__ pr =
        reinterpret_cast<const float4*>(p + (size_t)gwave * 512);

    float xx = 0.f, pp = 0.f, xp = 0.f;

#pragma unroll
    for (int i = 0; i < 2; ++i) {
        float4 a = xr[lane + 64 * i];
        float4 b = pr[lane + 64 * i];
        xx += a.x * a.x + a.y * a.y + a.z * a.z + a.w * a.w;
        pp += b.x * b.x + b.y * b.y + b.z * b.z + b.w * b.w;
        xp += a.x * b.x + a.y * b.y + a.z * b.z + a.w * b.w;
    }

    // 64-lane butterfly reduction (wave = 64 on CDNA).
#pragma unroll
    for (int off = 32; off > 0; off >>= 1) {
        xx += __shfl_xor(xx, off, 64);
        pp += __shfl_xor(pp, off, 64);
        xp += __shfl_xor(xp, off, 64);
    }

    if (lane == 0) {
        float denom = fmaxf(sqrtf(xx), EPSF) * fmaxf(sqrtf(pp), EPSF);
        out[gwave] = xp / denom * scale[0];
    }
}

extern "C" void kernel_launch(void* const* d_in, const int* in_sizes, int n_in,
                              void* d_out, int out_size, void* d_ws, size_t ws_size,
                              hipStream_t stream) {
    const float* x     = (const float*)d_in[0];
    const float* p     = (const float*)d_in[1];
    const float* scale = (const float*)d_in[2];
    float* out = (float*)d_out;

    const int n = out_size;          // 131072 rows
    // 4 waves (rows) per 256-thread block.
    const int blocks = (n + 3) / 4;
    cossim_rows_kernel<<<blocks, 256, 0, stream>>>(x, p, scale, out, n);
}

// Round 2
// 90.249 us; speedup vs baseline: 1.0460x; 1.0460x over previous
//
#include <hip/hip_runtime.h>

// Rowwise cosine similarity * scale:
//   out[i] = scale * dot(x[i], p[i]) / (max(||x[i]||,eps) * max(||p[i]||,eps))
// n = 131072 rows, d = 512 f32. Memory-bound: ~537 MB read per call.
//
// Persistent grid-stride: 2048 blocks x 256 thr = 8192 waves, 16 rows/wave.
// 2 rows per inner iteration -> 8 x 16B nontemporal loads in flight before
// the (serially-dependent) shuffle reductions; the two rows' reduction
// chains interleave. One 64-lane wave per row: lane i holds elements
// [8i..8i+8), butterfly __shfl_xor reduce, lane 0 writes.

typedef float f32x4 __attribute__((ext_vector_type(4)));

#define EPSF 1e-12f

__device__ __forceinline__ f32x4 ntload(const f32x4* p) {
    return __builtin_nontemporal_load(p);
}

__device__ __forceinline__ float dot4(f32x4 a, f32x4 b) {
    return a.x * b.x + a.y * b.y + a.z * b.z + a.w * b.w;
}

__global__ __launch_bounds__(256) void cossim_rows_kernel(
    const f32x4* __restrict__ x4,
    const f32x4* __restrict__ p4,
    const float* __restrict__ scale,
    float* __restrict__ out,
    int n, int nwaves)
{
    const int wid  = (int)((blockIdx.x * 256u + threadIdx.x) >> 6);
    const int lane = threadIdx.x & 63;
    const float s  = scale[0];

    int row = wid;
    // 2-row unrolled main loop: 8 loads in flight, 2 independent reduce chains.
    for (; row + nwaves < n; row += 2 * nwaves) {
        const int row1 = row + nwaves;
        const f32x4* xr0 = x4 + (size_t)row  * 128;
        const f32x4* pr0 = p4 + (size_t)row  * 128;
        const f32x4* xr1 = x4 + (size_t)row1 * 128;
        const f32x4* pr1 = p4 + (size_t)row1 * 128;

        f32x4 a0 = ntload(xr0 + lane);
        f32x4 a1 = ntload(xr0 + lane + 64);
        f32x4 b0 = ntload(pr0 + lane);
        f32x4 b1 = ntload(pr0 + lane + 64);
        f32x4 c0 = ntload(xr1 + lane);
        f32x4 c1 = ntload(xr1 + lane + 64);
        f32x4 d0 = ntload(pr1 + lane);
        f32x4 d1 = ntload(pr1 + lane + 64);

        float xx0 = dot4(a0, a0) + dot4(a1, a1);
        float pp0 = dot4(b0, b0) + dot4(b1, b1);
        float xp0 = dot4(a0, b0) + dot4(a1, b1);
        float xx1 = dot4(c0, c0) + dot4(c1, c1);
        float pp1 = dot4(d0, d0) + dot4(d1, d1);
        float xp1 = dot4(c0, d0) + dot4(c1, d1);

#pragma unroll
        for (int off = 32; off > 0; off >>= 1) {
            xx0 += __shfl_xor(xx0, off, 64);
            pp0 += __shfl_xor(pp0, off, 64);
            xp0 += __shfl_xor(xp0, off, 64);
            xx1 += __shfl_xor(xx1, off, 64);
            pp1 += __shfl_xor(pp1, off, 64);
            xp1 += __shfl_xor(xp1, off, 64);
        }

        if (lane == 0) {
            out[row]  = xp0 / (fmaxf(sqrtf(xx0), EPSF) * fmaxf(sqrtf(pp0), EPSF)) * s;
            out[row1] = xp1 / (fmaxf(sqrtf(xx1), EPSF) * fmaxf(sqrtf(pp1), EPSF)) * s;
        }
    }
    // Remainder (generic n).
    for (; row < n; row += nwaves) {
        const f32x4* xr = x4 + (size_t)row * 128;
        const f32x4* pr = p4 + (size_t)row * 128;

        f32x4 a0 = ntload(xr + lane);
        f32x4 a1 = ntload(xr + lane + 64);
        f32x4 b0 = ntload(pr + lane);
        f32x4 b1 = ntload(pr + lane + 64);

        float xx = dot4(a0, a0) + dot4(a1, a1);
        float pp = dot4(b0, b0) + dot4(b1, b1);
        float xp = dot4(a0, b0) + dot4(a1, b1);

#pragma unroll
        for (int off = 32; off > 0; off >>= 1) {
            xx += __shfl_xor(xx, off, 64);
            pp += __shfl_xor(pp, off, 64);
            xp += __shfl_xor(xp, off, 64);
        }

        if (lane == 0)
            out[row] = xp / (fmaxf(sqrtf(xx), EPSF) * fmaxf(sqrtf(pp), EPSF)) * s;
    }
}

extern "C" void kernel_launch(void* const* d_in, const int* in_sizes, int n_in,
                              void* d_out, int out_size, void* d_ws, size_t ws_size,
                              hipStream_t stream) {
    const f32x4* x4    = (const f32x4*)d_in[0];
    const f32x4* p4    = (const f32x4*)d_in[1];
    const float* scale = (const float*)d_in[2];
    float* out = (float*)d_out;

    const int n = out_size;              // 131072 rows
    const int blocks = 2048;             // 8 blocks/CU on 256 CUs
    const int nwaves = blocks * (256 / 64);
    cossim_rows_kernel<<<blocks, 256, 0, stream>>>(x4, p4, scale, out, n, nwaves);
}

// Round 3
// 85.333 us; speedup vs baseline: 1.1063x; 1.0576x over previous
//
#include <hip/hip_runtime.h>

// Rowwise cosine similarity * scale:
//   out[i] = scale * dot(x[i], p[i]) / (max(||x[i]||,eps) * max(||p[i]||,eps))
// n = 131072 rows, d = 512 f32. Memory-bound: ~537 MB read per call.
//
// Persistent grid-stride, 2048 blocks x 256 thr = 8192 waves, 16 rows/wave.
// Split-wave layout: per iteration a wave handles TWO rows — lanes 0..31 own
// row r, lanes 32..63 own row r+nwaves. Each lane loads 16 contiguous floats
// (4x float4, nontemporal) from x and p of its row, accumulates xx/pp/xp,
// then ONE 5-step butterfly (xor 16..1, stays within each 32-lane half)
// reduces both rows simultaneously: 15 shuffles/iter vs 36 in the 64-lane
// scheme. Lane 0 and lane 32 write their row's result.

typedef float f32x4 __attribute__((ext_vector_type(4)));

#define EPSF 1e-12f

__device__ __forceinline__ f32x4 ntload(const f32x4* p) {
    return __builtin_nontemporal_load(p);
}

__device__ __forceinline__ float dot4(f32x4 a, f32x4 b) {
    return a.x * b.x + a.y * b.y + a.z * b.z + a.w * b.w;
}

__global__ __launch_bounds__(256) void cossim_rows_kernel(
    const f32x4* __restrict__ x4,
    const f32x4* __restrict__ p4,
    const float* __restrict__ scale,
    float* __restrict__ out,
    int n, int nwaves)
{
    const int wid  = (int)((blockIdx.x * 256u + threadIdx.x) >> 6);
    const int lane = threadIdx.x & 63;
    const int half = lane >> 5;          // 0: row r, 1: row r+nwaves
    const int l32  = lane & 31;
    const float s  = scale[0];

    int row = wid;
    // Main loop: 2 rows per iteration via the 32-lane split.
    for (; row + nwaves < n; row += 2 * nwaves) {
        const int myrow = row + half * nwaves;
        const f32x4* xr = x4 + (size_t)myrow * 128;
        const f32x4* pr = p4 + (size_t)myrow * 128;

        f32x4 a0 = ntload(xr + l32);
        f32x4 a1 = ntload(xr + l32 + 32);
        f32x4 a2 = ntload(xr + l32 + 64);
        f32x4 a3 = ntload(xr + l32 + 96);
        f32x4 b0 = ntload(pr + l32);
        f32x4 b1 = ntload(pr + l32 + 32);
        f32x4 b2 = ntload(pr + l32 + 64);
        f32x4 b3 = ntload(pr + l32 + 96);

        float xx = dot4(a0, a0) + dot4(a1, a1) + dot4(a2, a2) + dot4(a3, a3);
        float pp = dot4(b0, b0) + dot4(b1, b1) + dot4(b2, b2) + dot4(b3, b3);
        float xp = dot4(a0, b0) + dot4(a1, b1) + dot4(a2, b2) + dot4(a3, b3);

        // 5-step butterfly within each 32-lane half (xor offsets < 32).
#pragma unroll
        for (int off = 16; off > 0; off >>= 1) {
            xx += __shfl_xor(xx, off, 64);
            pp += __shfl_xor(pp, off, 64);
            xp += __shfl_xor(xp, off, 64);
        }

        if (l32 == 0) {
            out[myrow] = xp / (fmaxf(sqrtf(xx), EPSF) * fmaxf(sqrtf(pp), EPSF)) * s;
        }
    }
    // Remainder (generic n): classic 64-lane single-row path.
    for (; row < n; row += nwaves) {
        const f32x4* xr = x4 + (size_t)row * 128;
        const f32x4* pr = p4 + (size_t)row * 128;

        f32x4 a0 = ntload(xr + lane);
        f32x4 a1 = ntload(xr + lane + 64);
        f32x4 b0 = ntload(pr + lane);
        f32x4 b1 = ntload(pr + lane + 64);

        float xx = dot4(a0, a0) + dot4(a1, a1);
        float pp = dot4(b0, b0) + dot4(b1, b1);
        float xp = dot4(a0, b0) + dot4(a1, b1);

#pragma unroll
        for (int off = 32; off > 0; off >>= 1) {
            xx += __shfl_xor(xx, off, 64);
            pp += __shfl_xor(pp, off, 64);
            xp += __shfl_xor(xp, off, 64);
        }

        if (lane == 0)
            out[row] = xp / (fmaxf(sqrtf(xx), EPSF) * fmaxf(sqrtf(pp), EPSF)) * s;
    }
}

extern "C" void kernel_launch(void* const* d_in, const int* in_sizes, int n_in,
                              void* d_out, int out_size, void* d_ws, size_t ws_size,
                              hipStream_t stream) {
    const f32x4* x4    = (const f32x4*)d_in[0];
    const f32x4* p4    = (const f32x4*)d_in[1];
    const float* scale = (const float*)d_in[2];
    float* out = (float*)d_out;

    const int n = out_size;              // 131072 rows
    const int blocks = 2048;             // 8 blocks/CU on 256 CUs
    const int nwaves = blocks * (256 / 64);
    cossim_rows_kernel<<<blocks, 256, 0, stream>>>(x4, p4, scale, out, n, nwaves);
}